// Round 1
// baseline (1111.106 us; speedup 1.0000x reference)
//
#include <hip/hip_runtime.h>

#define NTOK  384
#define SPANS 73920          // 384*385/2
#define MPAD  73984          // 578*128
#define MTILES 578
#define HD    1024

typedef unsigned short u16;
typedef __attribute__((ext_vector_type(8))) short short8;
typedef __attribute__((ext_vector_type(4))) float floatx4;

__device__ __forceinline__ u16 f2bu(float x) {
  union { float f; unsigned u; } un; un.f = x;
  unsigned r = un.u + 0x7fffu + ((un.u >> 16) & 1u);   // RNE
  return (u16)(r >> 16);
}

__device__ __forceinline__ void gld_lds16(const void* g, void* l) {
  __builtin_amdgcn_global_load_lds(
      (const __attribute__((address_space(1))) void*)g,
      (__attribute__((address_space(3))) void*)l, 16, 0, 0);
}

// ---- prep: prefix sums over token embeddings (concat(pos, word)) ----
__global__ void prep_pref(const int* __restrict__ sent, const int* __restrict__ pos,
                          const float* __restrict__ Wwrd, const float* __restrict__ Wpos,
                          float* __restrict__ pref) {
  int c = blockIdx.x * 256 + threadIdx.x;   // 0..1023
  float s = 0.f;
  pref[c] = 0.f;
  for (int t = 0; t < NTOK; ++t) {
    float v = (c < 512) ? Wpos[(size_t)pos[t] * 512 + c]
                        : Wwrd[(size_t)sent[t] * 512 + (c - 512)];
    s += v;
    pref[(size_t)(t + 1) * HD + c] = s;
  }
}

// ---- prep: span (i, end, 1/len) from linear triangular index ----
__global__ void prep_spans(int* __restrict__ spI, int* __restrict__ spE, float* __restrict__ spInv) {
  int rf = blockIdx.x * 256 + threadIdx.x;
  if (rf >= MPAD) return;
  int s = rf < SPANS ? rf : SPANS - 1;
  const int n = NTOK;
  double tn = 2.0 * n + 1.0;
  int i = (int)((tn - sqrt(tn * tn - 8.0 * (double)s)) * 0.5);
  if (i < 0) i = 0;
  if (i > n - 1) i = n - 1;
  #define OFF(ii) (((ii) * (2 * n - (ii) + 1)) / 2)
  while (i + 1 <= n - 1 && OFF(i + 1) <= s) ++i;
  while (i > 0 && OFF(i) > s) --i;
  int j = i + (s - OFF(i));
  #undef OFF
  spI[rf] = i;
  spE[rf] = j + 1;
  spInv[rf] = 1.0f / (float)(j + 1 - i);
}

// ---- prep: transpose+cast the three 1024x1024 weight blocks to bf16 B^T [N][K] ----
__global__ void prep_castT(const float* __restrict__ Wd1, const float* __restrict__ Wd2,
                           const float* __restrict__ Ws1,
                           u16* __restrict__ o1, u16* __restrict__ o2, u16* __restrict__ o3) {
  int b = blockIdx.x;           // 3*1024 blocks
  int w = b >> 10, rem = b & 1023;
  int tk = rem >> 5, tn = rem & 31;
  const float* src = (w == 0) ? Wd1 : ((w == 1) ? Wd2 : Ws1);
  u16* dst = (w == 0) ? o1 : ((w == 1) ? o2 : o3);
  __shared__ u16 tile[32][33];
  int x = threadIdx.x & 31, y = threadIdx.x >> 5;   // y in 0..7
  int k0 = tk * 32, n0 = tn * 32;
  for (int yy = 0; yy < 32; yy += 8)
    tile[y + yy][x] = f2bu(src[(size_t)(k0 + y + yy) * HD + n0 + x]);
  __syncthreads();
  for (int yy = 0; yy < 32; yy += 8)
    dst[(size_t)(n0 + y + yy) * HD + k0 + x] = tile[x][y + yy];
}

// ---- prep: S0/S1/S2 = column sums of W_s1's feat rows (len/start/end, 16 each), exact fp32 ----
__global__ void prep_svec(const float* __restrict__ Ws1,
                          float* __restrict__ S0, float* __restrict__ S1v, float* __restrict__ S2v) {
  int c = blockIdx.x * 256 + threadIdx.x;
  if (c >= HD) return;
  float a = 0.f, b = 0.f, d = 0.f;
  for (int r = 0; r < 16; ++r) {
    a += Ws1[(size_t)(1024 + r) * HD + c];
    b += Ws1[(size_t)(1040 + r) * HD + c];
    d += Ws1[(size_t)(1056 + r) * HD + c];
  }
  S0[c] = a; S1v[c] = b; S2v[c] = d;
}

// ---- prep: span means -> bf16 [MPAD][1024] ----
__global__ void prep_mean(const float* __restrict__ pref, const int* __restrict__ spI,
                          const int* __restrict__ spE, const float* __restrict__ spInv,
                          u16* __restrict__ out) {
  int gid = blockIdx.x * 256 + threadIdx.x;   // MPAD*128 threads
  int row = gid >> 7;
  int c0 = (gid & 127) << 3;
  int i = spI[row], e = spE[row];
  float inv = spInv[row];
  const float* pe = pref + (size_t)e * HD + c0;
  const float* pi = pref + (size_t)i * HD + c0;
  u16 tmp[8];
  #pragma unroll
  for (int u = 0; u < 8; ++u) tmp[u] = f2bu((pe[u] - pi[u]) * inv);
  *(uint4*)(out + (size_t)row * HD + c0) = *(const uint4*)tmp;
}

__global__ void scores_init(float* __restrict__ out, const float* __restrict__ bs2) {
  int g = blockIdx.x * 256 + threadIdx.x;
  if (g < SPANS) out[g] = bs2[0];
}

// ---- GEMM: C[M,1024] = relu(A[M,1024] @ B^T[1024,1024]^T + bias)  (m97 structure)
// EPI==0: store bf16 C.  EPI==1: + feats affine, relu, dot W_s2, atomicAdd scores.
template <int EPI>
__global__ __launch_bounds__(256) void gemm_bt(
    const u16* __restrict__ A, const u16* __restrict__ Bt,
    const float* __restrict__ bias, u16* __restrict__ C,
    const int* __restrict__ spI, const int* __restrict__ spE,
    const float* __restrict__ S0, const float* __restrict__ S1v, const float* __restrict__ S2v,
    const float* __restrict__ Ws2, float* __restrict__ scores) {
  __shared__ u16 As[128 * 64];   // [row][64] with octet XOR swizzle
  __shared__ u16 Bs[128 * 64];
  int bx = blockIdx.x;
  int mt = bx >> 3, nt = bx & 7;
  int m0 = mt * 128, n0 = nt * 128;
  int t = threadIdx.x, lane = t & 63, wid = t >> 6;
  int wm = wid >> 1, wn = wid & 1;
  int q = lane >> 4, r = lane & 15;

  floatx4 acc[4][4] = {};

  for (int kt = 0; kt < 16; ++kt) {
    #pragma unroll
    for (int it = 0; it < 4; ++it) {
      int cbase = wid * 64 + it * 256;          // wave-uniform
      int chunk = cbase + lane;
      int rowc = chunk >> 3;
      int oct = (chunk & 7) ^ (rowc & 7);       // XOR swizzle (bank-conflict fix)
      const u16* ga = A  + (size_t)(m0 + rowc) * HD + kt * 64 + oct * 8;
      const u16* gb = Bt + (size_t)(n0 + rowc) * HD + kt * 64 + oct * 8;
      gld_lds16(ga, &As[cbase * 8]);
      gld_lds16(gb, &Bs[cbase * 8]);
    }
    __syncthreads();
    #pragma unroll
    for (int kk = 0; kk < 2; ++kk) {
      short8 af[4], bf[4];
      #pragma unroll
      for (int x = 0; x < 4; ++x) {
        int rowA = wm * 64 + x * 16 + r;
        af[x] = *(const short8*)(As + (rowA * 8 + ((kk * 4 + q) ^ (rowA & 7))) * 8);
        int rowB = wn * 64 + x * 16 + r;
        bf[x] = *(const short8*)(Bs + (rowB * 8 + ((kk * 4 + q) ^ (rowB & 7))) * 8);
      }
      #pragma unroll
      for (int mi = 0; mi < 4; ++mi)
        #pragma unroll
        for (int ni = 0; ni < 4; ++ni)
          acc[mi][ni] = __builtin_amdgcn_mfma_f32_16x16x32_bf16(af[mi], bf[ni], acc[mi][ni], 0, 0, 0);
    }
    __syncthreads();
  }

  if (EPI == 0) {
    #pragma unroll
    for (int mi = 0; mi < 4; ++mi) {
      int rowb = m0 + wm * 64 + mi * 16 + q * 4;
      #pragma unroll
      for (int ni = 0; ni < 4; ++ni) {
        int col = n0 + wn * 64 + ni * 16 + r;
        float bcol = bias[col];
        #pragma unroll
        for (int e = 0; e < 4; ++e) {
          float v = acc[mi][ni][e] + bcol;
          v = v > 0.f ? v : 0.f;
          C[(size_t)(rowb + e) * HD + col] = f2bu(v);
        }
      }
    }
  } else {
    #pragma unroll
    for (int mi = 0; mi < 4; ++mi) {
      int rowb = m0 + wm * 64 + mi * 16 + q * 4;
      float psum[4];
      #pragma unroll
      for (int e = 0; e < 4; ++e) {
        int row = rowb + e;
        float fi = (float)spI[row];
        float fe = (float)spE[row];
        float fl = fe - fi;
        float p = 0.f;
        #pragma unroll
        for (int ni = 0; ni < 4; ++ni) {
          int col = n0 + wn * 64 + ni * 16 + r;
          float v = acc[mi][ni][e] + bias[col] + fl * S0[col] + fi * S1v[col] + fe * S2v[col];
          v = v > 0.f ? v : 0.f;
          p += v * Ws2[col];
        }
        psum[e] = p;
      }
      #pragma unroll
      for (int e = 0; e < 4; ++e) {
        float p = psum[e];
        p += __shfl_xor(p, 1);
        p += __shfl_xor(p, 2);
        p += __shfl_xor(p, 4);
        p += __shfl_xor(p, 8);
        int row = rowb + e;
        if (r == 0 && row < SPANS) atomicAdd(&scores[row], p);
      }
    }
  }
}

extern "C" void kernel_launch(void* const* d_in, const int* in_sizes, int n_in,
                              void* d_out, int out_size, void* d_ws, size_t ws_size,
                              hipStream_t stream) {
  const int*   sent = (const int*)d_in[0];
  const int*   pos  = (const int*)d_in[1];
  const float* Wwrd = (const float*)d_in[2];
  const float* Wpos = (const float*)d_in[3];
  const float* Wd1  = (const float*)d_in[4];
  const float* bd1  = (const float*)d_in[5];
  const float* Wd2  = (const float*)d_in[6];
  const float* bd2  = (const float*)d_in[7];
  const float* Ws1  = (const float*)d_in[8];
  const float* bs1  = (const float*)d_in[9];
  const float* Ws2  = (const float*)d_in[10];
  const float* bs2  = (const float*)d_in[11];
  float* scores = (float*)d_out;

  char* w = (char*)d_ws;
  size_t o = 0;
  auto alloc = [&](size_t bytes) {
    char* p = w + o;
    o = (o + bytes + 255) & ~(size_t)255;
    return p;
  };
  float* pref  = (float*)alloc((size_t)385 * HD * 4);
  int*   spI   = (int*)  alloc((size_t)MPAD * 4);
  int*   spE   = (int*)  alloc((size_t)MPAD * 4);
  float* spInv = (float*)alloc((size_t)MPAD * 4);
  float* S0    = (float*)alloc(4096);
  float* S1v   = (float*)alloc(4096);
  float* S2v   = (float*)alloc(4096);
  u16* Wd1t = (u16*)alloc((size_t)HD * HD * 2);
  u16* Wd2t = (u16*)alloc((size_t)HD * HD * 2);
  u16* Ws1t = (u16*)alloc((size_t)HD * HD * 2);
  u16* bufA = (u16*)alloc((size_t)MPAD * HD * 2);
  u16* bufB = (u16*)alloc((size_t)MPAD * HD * 2);

  prep_pref <<<4, 256, 0, stream>>>(sent, pos, Wwrd, Wpos, pref);
  prep_spans<<<(MPAD + 255) / 256, 256, 0, stream>>>(spI, spE, spInv);
  prep_castT<<<3 * 1024, 256, 0, stream>>>(Wd1, Wd2, Ws1, Wd1t, Wd2t, Ws1t);
  prep_svec <<<4, 256, 0, stream>>>(Ws1, S0, S1v, S2v);
  prep_mean <<<MPAD / 2, 256, 0, stream>>>(pref, spI, spE, spInv, bufA);
  scores_init<<<(SPANS + 255) / 256, 256, 0, stream>>>(scores, bs2);

  gemm_bt<0><<<MTILES * 8, 256, 0, stream>>>(bufA, Wd1t, bd1, bufB,
                                             nullptr, nullptr, nullptr, nullptr, nullptr, nullptr, nullptr);
  gemm_bt<0><<<MTILES * 8, 256, 0, stream>>>(bufB, Wd2t, bd2, bufA,
                                             nullptr, nullptr, nullptr, nullptr, nullptr, nullptr, nullptr);
  gemm_bt<1><<<MTILES * 8, 256, 0, stream>>>(bufA, Ws1t, bs1, nullptr,
                                             spI, spE, S0, S1v, S2v, Ws2, scores);
}

// Round 2
// 903.327 us; speedup vs baseline: 1.2300x; 1.2300x over previous
//
#include <hip/hip_runtime.h>

#define NTOK  384
#define SPANS 73920          // 384*385/2
#define MTILES 584           // 73*8 so grid=584*8 maps cleanly onto 8 XCDs
#define MPAD  (MTILES * 128) // 74752
#define HD    1024

typedef unsigned short u16;
typedef __attribute__((ext_vector_type(8))) short short8;
typedef __attribute__((ext_vector_type(4))) float floatx4;

__device__ __forceinline__ u16 f2bu(float x) {
  union { float f; unsigned u; } un; un.f = x;
  unsigned r = un.u + 0x7fffu + ((un.u >> 16) & 1u);   // RNE
  return (u16)(r >> 16);
}

__device__ __forceinline__ void gld_lds16(const void* g, void* l) {
  __builtin_amdgcn_global_load_lds(
      (const __attribute__((address_space(1))) void*)g,
      (__attribute__((address_space(3))) void*)l, 16, 0, 0);
}

// ---- prep: prefix sums via per-column parallel scan (block = one column) ----
__global__ void prep_pref(const int* __restrict__ sent, const int* __restrict__ pos,
                          const float* __restrict__ Wwrd, const float* __restrict__ Wpos,
                          float* __restrict__ pref) {
  __shared__ float buf[NTOK];
  int c = blockIdx.x;           // 0..1023
  int t = threadIdx.x;          // 0..383
  float v = (c < 512) ? Wpos[(size_t)pos[t] * 512 + c]
                      : Wwrd[(size_t)sent[t] * 512 + (c - 512)];
  buf[t] = v;
  __syncthreads();
  #pragma unroll
  for (int off = 1; off < NTOK; off <<= 1) {
    float add = (t >= off) ? buf[t - off] : 0.f;
    __syncthreads();
    buf[t] += add;
    __syncthreads();
  }
  if (t == 0) pref[c] = 0.f;
  pref[(size_t)(t + 1) * HD + c] = buf[t];
}

// ---- prep: span (i, end, 1/len) from linear triangular index ----
__global__ void prep_spans(int* __restrict__ spI, int* __restrict__ spE, float* __restrict__ spInv) {
  int rf = blockIdx.x * 256 + threadIdx.x;
  if (rf >= MPAD) return;
  int s = rf < SPANS ? rf : SPANS - 1;
  const int n = NTOK;
  double tn = 2.0 * n + 1.0;
  int i = (int)((tn - sqrt(tn * tn - 8.0 * (double)s)) * 0.5);
  if (i < 0) i = 0;
  if (i > n - 1) i = n - 1;
  #define OFF(ii) (((ii) * (2 * n - (ii) + 1)) / 2)
  while (i + 1 <= n - 1 && OFF(i + 1) <= s) ++i;
  while (i > 0 && OFF(i) > s) --i;
  int j = i + (s - OFF(i));
  #undef OFF
  spI[rf] = i;
  spE[rf] = j + 1;
  spInv[rf] = 1.0f / (float)(j + 1 - i);
}

// ---- prep: transpose+cast the three 1024x1024 weight blocks to bf16 B^T [N][K] ----
__global__ void prep_castT(const float* __restrict__ Wd1, const float* __restrict__ Wd2,
                           const float* __restrict__ Ws1,
                           u16* __restrict__ o1, u16* __restrict__ o2, u16* __restrict__ o3) {
  int b = blockIdx.x;           // 3*1024 blocks
  int w = b >> 10, rem = b & 1023;
  int tk = rem >> 5, tn = rem & 31;
  const float* src = (w == 0) ? Wd1 : ((w == 1) ? Wd2 : Ws1);
  u16* dst = (w == 0) ? o1 : ((w == 1) ? o2 : o3);
  __shared__ u16 tile[32][33];
  int x = threadIdx.x & 31, y = threadIdx.x >> 5;   // y in 0..7
  int k0 = tk * 32, n0 = tn * 32;
  for (int yy = 0; yy < 32; yy += 8)
    tile[y + yy][x] = f2bu(src[(size_t)(k0 + y + yy) * HD + n0 + x]);
  __syncthreads();
  for (int yy = 0; yy < 32; yy += 8)
    dst[(size_t)(n0 + y + yy) * HD + k0 + x] = tile[x][y + yy];
}

// ---- prep: S0/S1/S2 = column sums of W_s1's feat rows (len/start/end, 16 each), exact fp32 ----
__global__ void prep_svec(const float* __restrict__ Ws1,
                          float* __restrict__ S0, float* __restrict__ S1v, float* __restrict__ S2v) {
  int c = blockIdx.x * 256 + threadIdx.x;
  if (c >= HD) return;
  float a = 0.f, b = 0.f, d = 0.f;
  for (int r = 0; r < 16; ++r) {
    a += Ws1[(size_t)(1024 + r) * HD + c];
    b += Ws1[(size_t)(1040 + r) * HD + c];
    d += Ws1[(size_t)(1056 + r) * HD + c];
  }
  S0[c] = a; S1v[c] = b; S2v[c] = d;
}

// ---- prep: span means -> bf16 [MPAD][1024] ----
__global__ void prep_mean(const float* __restrict__ pref, const int* __restrict__ spI,
                          const int* __restrict__ spE, const float* __restrict__ spInv,
                          u16* __restrict__ out) {
  int gid = blockIdx.x * 256 + threadIdx.x;   // MPAD*128 threads
  int row = gid >> 7;
  int c0 = (gid & 127) << 3;
  int i = spI[row], e = spE[row];
  float inv = spInv[row];
  const float* pe = pref + (size_t)e * HD + c0;
  const float* pi = pref + (size_t)i * HD + c0;
  u16 tmp[8];
  #pragma unroll
  for (int u = 0; u < 8; ++u) tmp[u] = f2bu((pe[u] - pi[u]) * inv);
  *(uint4*)(out + (size_t)row * HD + c0) = *(const uint4*)tmp;
}

__global__ void scores_init(float* __restrict__ out, const float* __restrict__ bs2) {
  int g = blockIdx.x * 256 + threadIdx.x;
  if (g < SPANS) out[g] = bs2[0];
}

// ---- GEMM: C[M,1024] = relu(A[M,1024] @ B^T[1024,1024]^T + bias)  (m97 structure)
// Block mapping is XCD-aware: XCD x (= bx%8) owns all mt with mt%8==x,
// iterating nt fastest, so one A-panel is fetched once and reused 8x from L2.
// EPI==0: store bf16 C.  EPI==1: + feats affine, relu, dot W_s2, atomicAdd scores.
template <int EPI>
__global__ __launch_bounds__(256) void gemm_bt(
    const u16* __restrict__ A, const u16* __restrict__ Bt,
    const float* __restrict__ bias, u16* __restrict__ C,
    const int* __restrict__ spI, const int* __restrict__ spE,
    const float* __restrict__ S0, const float* __restrict__ S1v, const float* __restrict__ S2v,
    const float* __restrict__ Ws2, float* __restrict__ scores) {
  __shared__ u16 As[128 * 64];   // [row][64] with octet XOR swizzle
  __shared__ u16 Bs[128 * 64];
  int bx = blockIdx.x;
  int xcd = bx & 7, k = bx >> 3;
  int nt = k & 7;
  int mt = xcd + 8 * (k >> 3);     // mt%8 == xcd; 8 consecutive blocks per XCD share mt
  int m0 = mt * 128, n0 = nt * 128;
  int t = threadIdx.x, lane = t & 63, wid = t >> 6;
  int wm = wid >> 1, wn = wid & 1;
  int q = lane >> 4, r = lane & 15;

  floatx4 acc[4][4] = {};

  for (int kt = 0; kt < 16; ++kt) {
    #pragma unroll
    for (int it = 0; it < 4; ++it) {
      int cbase = wid * 64 + it * 256;          // wave-uniform
      int chunk = cbase + lane;
      int rowc = chunk >> 3;
      int oct = (chunk & 7) ^ (rowc & 7);       // XOR swizzle (bank-conflict fix)
      const u16* ga = A  + (size_t)(m0 + rowc) * HD + kt * 64 + oct * 8;
      const u16* gb = Bt + (size_t)(n0 + rowc) * HD + kt * 64 + oct * 8;
      gld_lds16(ga, &As[cbase * 8]);
      gld_lds16(gb, &Bs[cbase * 8]);
    }
    __syncthreads();
    #pragma unroll
    for (int kk = 0; kk < 2; ++kk) {
      short8 af[4], bf[4];
      #pragma unroll
      for (int x = 0; x < 4; ++x) {
        int rowA = wm * 64 + x * 16 + r;
        af[x] = *(const short8*)(As + (rowA * 8 + ((kk * 4 + q) ^ (rowA & 7))) * 8);
        int rowB = wn * 64 + x * 16 + r;
        bf[x] = *(const short8*)(Bs + (rowB * 8 + ((kk * 4 + q) ^ (rowB & 7))) * 8);
      }
      #pragma unroll
      for (int mi = 0; mi < 4; ++mi)
        #pragma unroll
        for (int ni = 0; ni < 4; ++ni)
          acc[mi][ni] = __builtin_amdgcn_mfma_f32_16x16x32_bf16(af[mi], bf[ni], acc[mi][ni], 0, 0, 0);
    }
    __syncthreads();
  }

  if (EPI == 0) {
    #pragma unroll
    for (int mi = 0; mi < 4; ++mi) {
      int rowb = m0 + wm * 64 + mi * 16 + q * 4;
      #pragma unroll
      for (int ni = 0; ni < 4; ++ni) {
        int col = n0 + wn * 64 + ni * 16 + r;
        float bcol = bias[col];
        #pragma unroll
        for (int e = 0; e < 4; ++e) {
          float v = acc[mi][ni][e] + bcol;
          v = v > 0.f ? v : 0.f;
          C[(size_t)(rowb + e) * HD + col] = f2bu(v);
        }
      }
    }
  } else {
    #pragma unroll
    for (int mi = 0; mi < 4; ++mi) {
      int rowb = m0 + wm * 64 + mi * 16 + q * 4;
      float psum[4];
      #pragma unroll
      for (int e = 0; e < 4; ++e) {
        int row = rowb + e;
        float fi = (float)spI[row];
        float fe = (float)spE[row];
        float fl = fe - fi;
        float p = 0.f;
        #pragma unroll
        for (int ni = 0; ni < 4; ++ni) {
          int col = n0 + wn * 64 + ni * 16 + r;
          float v = acc[mi][ni][e] + bias[col] + fl * S0[col] + fi * S1v[col] + fe * S2v[col];
          v = v > 0.f ? v : 0.f;
          p += v * Ws2[col];
        }
        psum[e] = p;
      }
      #pragma unroll
      for (int e = 0; e < 4; ++e) {
        float p = psum[e];
        p += __shfl_xor(p, 1);
        p += __shfl_xor(p, 2);
        p += __shfl_xor(p, 4);
        p += __shfl_xor(p, 8);
        int row = rowb + e;
        if (r == 0 && row < SPANS) atomicAdd(&scores[row], p);
      }
    }
  }
}

extern "C" void kernel_launch(void* const* d_in, const int* in_sizes, int n_in,
                              void* d_out, int out_size, void* d_ws, size_t ws_size,
                              hipStream_t stream) {
  const int*   sent = (const int*)d_in[0];
  const int*   pos  = (const int*)d_in[1];
  const float* Wwrd = (const float*)d_in[2];
  const float* Wpos = (const float*)d_in[3];
  const float* Wd1  = (const float*)d_in[4];
  const float* bd1  = (const float*)d_in[5];
  const float* Wd2  = (const float*)d_in[6];
  const float* bd2  = (const float*)d_in[7];
  const float* Ws1  = (const float*)d_in[8];
  const float* bs1  = (const float*)d_in[9];
  const float* Ws2  = (const float*)d_in[10];
  const float* bs2  = (const float*)d_in[11];
  float* scores = (float*)d_out;

  char* w = (char*)d_ws;
  size_t o = 0;
  auto alloc = [&](size_t bytes) {
    char* p = w + o;
    o = (o + bytes + 255) & ~(size_t)255;
    return p;
  };
  float* pref  = (float*)alloc((size_t)385 * HD * 4);
  int*   spI   = (int*)  alloc((size_t)MPAD * 4);
  int*   spE   = (int*)  alloc((size_t)MPAD * 4);
  float* spInv = (float*)alloc((size_t)MPAD * 4);
  float* S0    = (float*)alloc(4096);
  float* S1v   = (float*)alloc(4096);
  float* S2v   = (float*)alloc(4096);
  u16* Wd1t = (u16*)alloc((size_t)HD * HD * 2);
  u16* Wd2t = (u16*)alloc((size_t)HD * HD * 2);
  u16* Ws1t = (u16*)alloc((size_t)HD * HD * 2);
  u16* bufA = (u16*)alloc((size_t)MPAD * HD * 2);
  u16* bufB = (u16*)alloc((size_t)MPAD * HD * 2);

  prep_pref <<<HD, NTOK, 0, stream>>>(sent, pos, Wwrd, Wpos, pref);
  prep_spans<<<(MPAD + 255) / 256, 256, 0, stream>>>(spI, spE, spInv);
  prep_castT<<<3 * 1024, 256, 0, stream>>>(Wd1, Wd2, Ws1, Wd1t, Wd2t, Ws1t);
  prep_svec <<<4, 256, 0, stream>>>(Ws1, S0, S1v, S2v);
  prep_mean <<<MPAD / 2, 256, 0, stream>>>(pref, spI, spE, spInv, bufA);
  scores_init<<<(SPANS + 255) / 256, 256, 0, stream>>>(scores, bs2);

  gemm_bt<0><<<MTILES * 8, 256, 0, stream>>>(bufA, Wd1t, bd1, bufB,
                                             nullptr, nullptr, nullptr, nullptr, nullptr, nullptr, nullptr);
  gemm_bt<0><<<MTILES * 8, 256, 0, stream>>>(bufB, Wd2t, bd2, bufA,
                                             nullptr, nullptr, nullptr, nullptr, nullptr, nullptr, nullptr);
  gemm_bt<1><<<MTILES * 8, 256, 0, stream>>>(bufA, Ws1t, bs1, nullptr,
                                             spI, spE, S0, S1v, S2v, Ws2, scores);
}

// Round 3
// 791.317 us; speedup vs baseline: 1.4041x; 1.1415x over previous
//
#include <hip/hip_runtime.h>

#define NTOK  384
#define SPANS 73920          // 384*385/2
#define MTILES 584           // 73*8 so grid=584*8 maps cleanly onto 8 XCDs
#define MPAD  (MTILES * 128) // 74752
#define HD    1024

typedef unsigned short u16;
typedef __attribute__((ext_vector_type(8))) short short8;
typedef __attribute__((ext_vector_type(4))) float floatx4;

// gfx9 s_waitcnt immediate: vmcnt[3:0]|[15:14], expcnt[6:4], lgkmcnt[11:8]
#define VMCNT_IMM(N) (((N) & 0xF) | (((N) >> 4) << 14) | (0x7 << 4) | (0xF << 8))

__device__ __forceinline__ u16 f2bu(float x) {
  union { float f; unsigned u; } un; un.f = x;
  unsigned r = un.u + 0x7fffu + ((un.u >> 16) & 1u);   // RNE
  return (u16)(r >> 16);
}

__device__ __forceinline__ void gld_lds16(const void* g, void* l) {
  __builtin_amdgcn_global_load_lds(
      (const __attribute__((address_space(1))) void*)g,
      (__attribute__((address_space(3))) void*)l, 16, 0, 0);
}

// ---- prep: prefix sums via per-column parallel scan (block = one column) ----
__global__ void prep_pref(const int* __restrict__ sent, const int* __restrict__ pos,
                          const float* __restrict__ Wwrd, const float* __restrict__ Wpos,
                          float* __restrict__ pref) {
  __shared__ float buf[NTOK];
  int c = blockIdx.x;           // 0..1023
  int t = threadIdx.x;          // 0..383
  float v = (c < 512) ? Wpos[(size_t)pos[t] * 512 + c]
                      : Wwrd[(size_t)sent[t] * 512 + (c - 512)];
  buf[t] = v;
  __syncthreads();
  #pragma unroll
  for (int off = 1; off < NTOK; off <<= 1) {
    float add = (t >= off) ? buf[t - off] : 0.f;
    __syncthreads();
    buf[t] += add;
    __syncthreads();
  }
  if (t == 0) pref[c] = 0.f;
  pref[(size_t)(t + 1) * HD + c] = buf[t];
}

// ---- prep: span (i, end, 1/len) from linear triangular index ----
__global__ void prep_spans(int* __restrict__ spI, int* __restrict__ spE, float* __restrict__ spInv) {
  int rf = blockIdx.x * 256 + threadIdx.x;
  if (rf >= MPAD) return;
  int s = rf < SPANS ? rf : SPANS - 1;
  const int n = NTOK;
  double tn = 2.0 * n + 1.0;
  int i = (int)((tn - sqrt(tn * tn - 8.0 * (double)s)) * 0.5);
  if (i < 0) i = 0;
  if (i > n - 1) i = n - 1;
  #define OFF(ii) (((ii) * (2 * n - (ii) + 1)) / 2)
  while (i + 1 <= n - 1 && OFF(i + 1) <= s) ++i;
  while (i > 0 && OFF(i) > s) --i;
  int j = i + (s - OFF(i));
  #undef OFF
  spI[rf] = i;
  spE[rf] = j + 1;
  spInv[rf] = 1.0f / (float)(j + 1 - i);
}

// ---- prep: transpose+cast the three 1024x1024 weight blocks to bf16 B^T [N][K] ----
__global__ void prep_castT(const float* __restrict__ Wd1, const float* __restrict__ Wd2,
                           const float* __restrict__ Ws1,
                           u16* __restrict__ o1, u16* __restrict__ o2, u16* __restrict__ o3) {
  int b = blockIdx.x;           // 3*1024 blocks
  int w = b >> 10, rem = b & 1023;
  int tk = rem >> 5, tn = rem & 31;
  const float* src = (w == 0) ? Wd1 : ((w == 1) ? Wd2 : Ws1);
  u16* dst = (w == 0) ? o1 : ((w == 1) ? o2 : o3);
  __shared__ u16 tile[32][33];
  int x = threadIdx.x & 31, y = threadIdx.x >> 5;   // y in 0..7
  int k0 = tk * 32, n0 = tn * 32;
  for (int yy = 0; yy < 32; yy += 8)
    tile[y + yy][x] = f2bu(src[(size_t)(k0 + y + yy) * HD + n0 + x]);
  __syncthreads();
  for (int yy = 0; yy < 32; yy += 8)
    dst[(size_t)(n0 + y + yy) * HD + k0 + x] = tile[x][y + yy];
}

// ---- prep: S0/S1/S2 = column sums of W_s1's feat rows (len/start/end, 16 each), exact fp32 ----
__global__ void prep_svec(const float* __restrict__ Ws1,
                          float* __restrict__ S0, float* __restrict__ S1v, float* __restrict__ S2v) {
  int c = blockIdx.x * 256 + threadIdx.x;
  if (c >= HD) return;
  float a = 0.f, b = 0.f, d = 0.f;
  for (int r = 0; r < 16; ++r) {
    a += Ws1[(size_t)(1024 + r) * HD + c];
    b += Ws1[(size_t)(1040 + r) * HD + c];
    d += Ws1[(size_t)(1056 + r) * HD + c];
  }
  S0[c] = a; S1v[c] = b; S2v[c] = d;
}

// ---- prep: span means -> bf16 [MPAD][1024] ----
__global__ void prep_mean(const float* __restrict__ pref, const int* __restrict__ spI,
                          const int* __restrict__ spE, const float* __restrict__ spInv,
                          u16* __restrict__ out) {
  int gid = blockIdx.x * 256 + threadIdx.x;   // MPAD*128 threads
  int row = gid >> 7;
  int c0 = (gid & 127) << 3;
  int i = spI[row], e = spE[row];
  float inv = spInv[row];
  const float* pe = pref + (size_t)e * HD + c0;
  const float* pi = pref + (size_t)i * HD + c0;
  u16 tmp[8];
  #pragma unroll
  for (int u = 0; u < 8; ++u) tmp[u] = f2bu((pe[u] - pi[u]) * inv);
  *(uint4*)(out + (size_t)row * HD + c0) = *(const uint4*)tmp;
}

__global__ void scores_init(float* __restrict__ out, const float* __restrict__ bs2) {
  int g = blockIdx.x * 256 + threadIdx.x;
  if (g < SPANS) out[g] = bs2[0];
}

// ---- GEMM: C[M,1024] = relu(A[M,1024] @ B^T[1024,1024]^T + bias)
// XCD-aware block mapping + ping-pong LDS double buffer with raw s_barrier and
// fine-grained vmcnt(8) (never drain to 0 mid-loop): kt+1's global_load_lds
// stays in flight while kt computes, hiding the HBM/L2 staging latency that
// the 2-barrier structure exposed.
// EPI==0: store bf16 C.  EPI==1: + feats affine, relu, dot W_s2, atomicAdd scores.
template <int EPI>
__global__ __launch_bounds__(256) void gemm_bt(
    const u16* __restrict__ A, const u16* __restrict__ Bt,
    const float* __restrict__ bias, u16* __restrict__ C,
    const int* __restrict__ spI, const int* __restrict__ spE,
    const float* __restrict__ S0, const float* __restrict__ S1v, const float* __restrict__ S2v,
    const float* __restrict__ Ws2, float* __restrict__ scores) {
  __shared__ u16 As[2][128 * 64];   // [row][64] with octet XOR swizzle
  __shared__ u16 Bs[2][128 * 64];
  int bx = blockIdx.x;
  int xcd = bx & 7, k = bx >> 3;
  int nt = k & 7;
  int mt = xcd + 8 * (k >> 3);     // mt%8 == xcd; 8 consecutive blocks per XCD share mt
  int m0 = mt * 128, n0 = nt * 128;
  int t = threadIdx.x, lane = t & 63, wid = t >> 6;
  int wm = wid >> 1, wn = wid & 1;
  int q = lane >> 4, r = lane & 15;

  floatx4 acc[4][4] = {};

  // per-wave staging geometry (wave-uniform LDS base, lane-scatter source)
  int cbase0 = wid * 64;
  int chunk = cbase0 + lane;
  int rowc = chunk >> 3;
  int oct = (chunk & 7) ^ (rowc & 7);          // XOR swizzle (bank-conflict fix)
  const u16* gA = A  + (size_t)(m0 + rowc) * HD + oct * 8;
  const u16* gB = Bt + (size_t)(n0 + rowc) * HD + oct * 8;

  auto stage = [&](int kt, int b) {
    #pragma unroll
    for (int it = 0; it < 4; ++it) {
      int cb = cbase0 + it * 256;
      int rofs = it * 32;                       // rows advance 32 per it
      gld_lds16(gA + (size_t)rofs * HD + kt * 64, &As[b][cb * 8]);
      gld_lds16(gB + (size_t)rofs * HD + kt * 64, &Bs[b][cb * 8]);
    }
  };

  auto compute = [&](int b) {
    #pragma unroll
    for (int kk = 0; kk < 2; ++kk) {
      short8 af[4], bf[4];
      #pragma unroll
      for (int x = 0; x < 4; ++x) {
        int rowA = wm * 64 + x * 16 + r;
        af[x] = *(const short8*)(&As[b][0] + (rowA * 8 + ((kk * 4 + q) ^ (rowA & 7))) * 8);
        int rowB = wn * 64 + x * 16 + r;
        bf[x] = *(const short8*)(&Bs[b][0] + (rowB * 8 + ((kk * 4 + q) ^ (rowB & 7))) * 8);
      }
      #pragma unroll
      for (int mi = 0; mi < 4; ++mi)
        #pragma unroll
        for (int ni = 0; ni < 4; ++ni)
          acc[mi][ni] = __builtin_amdgcn_mfma_f32_16x16x32_bf16(af[mi], bf[ni], acc[mi][ni], 0, 0, 0);
    }
  };

  stage(0, 0);
  #pragma unroll 1
  for (int kp = 0; kp < 8; ++kp) {
    int kt0 = 2 * kp;
    stage(kt0 + 1, 1);                              // prefetch odd
    __builtin_amdgcn_s_waitcnt(VMCNT_IMM(8));       // wait even's 8, prefetch in flight
    __builtin_amdgcn_s_barrier();
    compute(0);
    __builtin_amdgcn_s_barrier();                   // all done reading buf0
    if (kp < 7) {
      stage(kt0 + 2, 0);                            // prefetch next even
      __builtin_amdgcn_s_waitcnt(VMCNT_IMM(8));
    } else {
      __builtin_amdgcn_s_waitcnt(VMCNT_IMM(0));
    }
    __builtin_amdgcn_s_barrier();
    compute(1);
    __builtin_amdgcn_s_barrier();                   // all done reading buf1
  }

  if (EPI == 0) {
    #pragma unroll
    for (int mi = 0; mi < 4; ++mi) {
      int rowb = m0 + wm * 64 + mi * 16 + q * 4;
      #pragma unroll
      for (int ni = 0; ni < 4; ++ni) {
        int col = n0 + wn * 64 + ni * 16 + r;
        float bcol = bias[col];
        #pragma unroll
        for (int e = 0; e < 4; ++e) {
          float v = acc[mi][ni][e] + bcol;
          v = v > 0.f ? v : 0.f;
          C[(size_t)(rowb + e) * HD + col] = f2bu(v);
        }
      }
    }
  } else {
    #pragma unroll
    for (int mi = 0; mi < 4; ++mi) {
      int rowb = m0 + wm * 64 + mi * 16 + q * 4;
      float psum[4];
      #pragma unroll
      for (int e = 0; e < 4; ++e) {
        int row = rowb + e;
        float fi = (float)spI[row];
        float fe = (float)spE[row];
        float fl = fe - fi;
        float p = 0.f;
        #pragma unroll
        for (int ni = 0; ni < 4; ++ni) {
          int col = n0 + wn * 64 + ni * 16 + r;
          float v = acc[mi][ni][e] + bias[col] + fl * S0[col] + fi * S1v[col] + fe * S2v[col];
          v = v > 0.f ? v : 0.f;
          p += v * Ws2[col];
        }
        psum[e] = p;
      }
      #pragma unroll
      for (int e = 0; e < 4; ++e) {
        float p = psum[e];
        p += __shfl_xor(p, 1);
        p += __shfl_xor(p, 2);
        p += __shfl_xor(p, 4);
        p += __shfl_xor(p, 8);
        int row = rowb + e;
        if (r == 0 && row < SPANS) atomicAdd(&scores[row], p);
      }
    }
  }
}

extern "C" void kernel_launch(void* const* d_in, const int* in_sizes, int n_in,
                              void* d_out, int out_size, void* d_ws, size_t ws_size,
                              hipStream_t stream) {
  const int*   sent = (const int*)d_in[0];
  const int*   pos  = (const int*)d_in[1];
  const float* Wwrd = (const float*)d_in[2];
  const float* Wpos = (const float*)d_in[3];
  const float* Wd1  = (const float*)d_in[4];
  const float* bd1  = (const float*)d_in[5];
  const float* Wd2  = (const float*)d_in[6];
  const float* bd2  = (const float*)d_in[7];
  const float* Ws1  = (const float*)d_in[8];
  const float* bs1  = (const float*)d_in[9];
  const float* Ws2  = (const float*)d_in[10];
  const float* bs2  = (const float*)d_in[11];
  float* scores = (float*)d_out;

  char* w = (char*)d_ws;
  size_t o = 0;
  auto alloc = [&](size_t bytes) {
    char* p = w + o;
    o = (o + bytes + 255) & ~(size_t)255;
    return p;
  };
  float* pref  = (float*)alloc((size_t)385 * HD * 4);
  int*   spI   = (int*)  alloc((size_t)MPAD * 4);
  int*   spE   = (int*)  alloc((size_t)MPAD * 4);
  float* spInv = (float*)alloc((size_t)MPAD * 4);
  float* S0    = (float*)alloc(4096);
  float* S1v   = (float*)alloc(4096);
  float* S2v   = (float*)alloc(4096);
  u16* Wd1t = (u16*)alloc((size_t)HD * HD * 2);
  u16* Wd2t = (u16*)alloc((size_t)HD * HD * 2);
  u16* Ws1t = (u16*)alloc((size_t)HD * HD * 2);
  u16* bufA = (u16*)alloc((size_t)MPAD * HD * 2);
  u16* bufB = (u16*)alloc((size_t)MPAD * HD * 2);

  prep_pref <<<HD, NTOK, 0, stream>>>(sent, pos, Wwrd, Wpos, pref);
  prep_spans<<<(MPAD + 255) / 256, 256, 0, stream>>>(spI, spE, spInv);
  prep_castT<<<3 * 1024, 256, 0, stream>>>(Wd1, Wd2, Ws1, Wd1t, Wd2t, Ws1t);
  prep_svec <<<4, 256, 0, stream>>>(Ws1, S0, S1v, S2v);
  prep_mean <<<MPAD / 2, 256, 0, stream>>>(pref, spI, spE, spInv, bufA);
  scores_init<<<(SPANS + 255) / 256, 256, 0, stream>>>(scores, bs2);

  gemm_bt<0><<<MTILES * 8, 256, 0, stream>>>(bufA, Wd1t, bd1, bufB,
                                             nullptr, nullptr, nullptr, nullptr, nullptr, nullptr, nullptr);
  gemm_bt<0><<<MTILES * 8, 256, 0, stream>>>(bufB, Wd2t, bd2, bufA,
                                             nullptr, nullptr, nullptr, nullptr, nullptr, nullptr, nullptr);
  gemm_bt<1><<<MTILES * 8, 256, 0, stream>>>(bufA, Ws1t, bs1, nullptr,
                                             spI, spE, S0, S1v, S2v, Ws2, scores);
}